// Round 1
// baseline (94685.028 us; speedup 1.0000x reference)
//
#include <hip/hip_runtime.h>
#include <cstdio>

#define NROWS 8640      // D*T = 90*96 sequential steps
#define HDIM  1024
#define GWG   256       // persistent workgroups (barrier slots)

typedef float vf4 __attribute__((ext_vector_type(4)));
typedef int   vi4 __attribute__((ext_vector_type(4)));

__device__ __forceinline__ float fsig(float x)  { return 1.f / (1.f + __expf(-x)); }
__device__ __forceinline__ float ftanh(float x) { return 2.f / (1.f + __expf(-2.f * x)) - 1.f; }

// ---------- LLC-coherent (cross-XCD) access helpers: sc0 sc1 bypass L1/L2 ----------
__device__ __forceinline__ void llc_load16(const float* p, vf4& a, vf4& b, vf4& c, vf4& d) {
  asm volatile(
      "global_load_dwordx4 %0, %4, off sc0 sc1\n\t"
      "global_load_dwordx4 %1, %4, off offset:1024 sc0 sc1\n\t"
      "global_load_dwordx4 %2, %4, off offset:2048 sc0 sc1\n\t"
      "global_load_dwordx4 %3, %4, off offset:3072 sc0 sc1\n\t"
      "s_waitcnt vmcnt(0)"
      : "=v"(a), "=v"(b), "=v"(c), "=v"(d)
      : "v"(p)
      : "memory");
}
__device__ __forceinline__ void llc_store_f(float* p, float v) {
  asm volatile("global_store_dword %0, %1, off sc0 sc1" :: "v"(p), "v"(v) : "memory");
}
__device__ __forceinline__ void llc_store_i(int* p, int v) {
  asm volatile("global_store_dword %0, %1, off sc0 sc1" :: "v"(p), "v"(v) : "memory");
}
__device__ __forceinline__ vi4 llc_load_i4(const int* p) {
  vi4 v;
  asm volatile("global_load_dwordx4 %0, %1, off sc0 sc1\n\ts_waitcnt vmcnt(0)"
               : "=v"(v) : "v"(p) : "memory");
  return v;
}

// All-poll-all grid barrier. arrive[] monotonically counts phases; every WG posts
// its own slot (no RMW contention) and wave 0 checks all 256 slots with one
// dwordx4 LLC load per lane. Entry s_waitcnt drains this wave's data stores
// (all cross-WG data uses write-through sc0sc1 stores -> no L2 writeback needed).
__device__ __forceinline__ void gridbar(int* arrive, int p) {
  asm volatile("s_waitcnt vmcnt(0)" ::: "memory");
  __syncthreads();
  if (threadIdx.x == 0) llc_store_i(&arrive[blockIdx.x], p);
  if (threadIdx.x < 64) {
    const int* slot = arrive + (threadIdx.x << 2);
    for (;;) {
      vi4 v = llc_load_i4(slot);
      int ok = (v.x >= p) & (v.y >= p) & (v.z >= p) & (v.w >= p);
      if (__all(ok)) break;
      __builtin_amdgcn_s_sleep(2);
    }
  }
  __syncthreads();
}

__device__ __forceinline__ float dotW(const vf4* Wr, vf4 a, vf4 b, vf4 c, vf4 d) {
  float s;
  s  = Wr[0].x*a.x + Wr[0].y*a.y + Wr[0].z*a.z + Wr[0].w*a.w;
  s += Wr[1].x*b.x + Wr[1].y*b.y + Wr[1].z*b.z + Wr[1].w*b.w;
  s += Wr[2].x*c.x + Wr[2].y*c.y + Wr[2].z*c.z + Wr[2].w*c.w;
  s += Wr[3].x*d.x + Wr[3].y*d.y + Wr[3].z*d.z + Wr[3].w*d.w;
  return s;
}

// ---------- persistent sequential LSTM scan ----------
// 256 WGs x 4 waves; wave owns hidden index j = wg*4+wave and holds rows
// w_t[j], w_oh[j], w_ih[j], w_gh[j], w_fo[j] in registers (lane l holds
// elements 256*m + 4*l + q, matching llc_load16's layout of h).
__global__ __launch_bounds__(256, 2) void scan_kernel(
    const float* __restrict__ pre_ho, const float* __restrict__ pre_i,
    const float* __restrict__ pre_g,  const float* __restrict__ pre_f,
    const float* __restrict__ pre_o,
    const float* __restrict__ w_t,  const float* __restrict__ w_ih,
    const float* __restrict__ w_gh, const float* __restrict__ w_fo,
    const float* __restrict__ w_oh,
    float* __restrict__ hbuf, float* __restrict__ hobuf,
    int* __restrict__ arrive,
    float* __restrict__ hs, float* __restrict__ cs)
{
  const int tid  = threadIdx.x;
  const int lane = tid & 63;
  const int j    = (blockIdx.x << 2) + (tid >> 6);

  vf4 W[5][4];
  {
    const float* rp[5] = { w_t + j*HDIM, w_oh + j*HDIM, w_ih + j*HDIM,
                           w_gh + j*HDIM, w_fo + j*HDIM };
#pragma unroll
    for (int r = 0; r < 5; ++r)
#pragma unroll
      for (int m = 0; m < 4; ++m)
        W[r][m] = *(const vf4*)(rp[r] + m*256 + (lane << 2));
  }

  float cprev = 0.f;
  float ph = pre_ho[j], po = pre_o[j];   // phase-A operands, prefetched
  float pi, pg, pf;

  for (int n = 0; n < NROWS; ++n) {
    // ---- phase A: h_o = sig(ph + 2*w_t@h_prev); o = sig(po + w_oh@h_prev) ----
    float ut = 0.f, uo = 0.f;
    if (n > 0) {
      vf4 a, b, c, d;
      llc_load16(hbuf + (lane << 2), a, b, c, d);
      pi = pre_i[n*HDIM + j]; pg = pre_g[n*HDIM + j]; pf = pre_f[n*HDIM + j];
      ut = dotW(W[0], a, b, c, d);
      uo = dotW(W[1], a, b, c, d);
#pragma unroll
      for (int off = 32; off; off >>= 1) {
        ut += __shfl_xor(ut, off, 64);
        uo += __shfl_xor(uo, off, 64);
      }
    } else {
      pi = pre_i[j]; pg = pre_g[j]; pf = pre_f[j];
    }
    float ho = fsig(ph + 2.f * ut);
    float oo = fsig(po + uo);
    if (lane == 0) llc_store_f(&hobuf[j], ho);
    gridbar(arrive, 2*n + 1);

    // ---- phase B: gates from h_o, update c, h ----
    vf4 a, b, c, d;
    llc_load16(hobuf + (lane << 2), a, b, c, d);
    if (n + 1 < NROWS) { ph = pre_ho[(n+1)*HDIM + j]; po = pre_o[(n+1)*HDIM + j]; }
    float ui = dotW(W[2], a, b, c, d);
    float ug = dotW(W[3], a, b, c, d);
    float uf = dotW(W[4], a, b, c, d);
#pragma unroll
    for (int off = 32; off; off >>= 1) {
      ui += __shfl_xor(ui, off, 64);
      ug += __shfl_xor(ug, off, 64);
      uf += __shfl_xor(uf, off, 64);
    }
    float ii = fsig(pi + ui);
    float gg = ftanh(pg + ug);
    float ff = fsig(pf + uf);
    float cc = ff * cprev + ii * gg;
    float hh = oo * ftanh(cc);
    cprev = cc;
    if (lane == 0) {
      llc_store_f(&hbuf[j], hh);
      hs[n*HDIM + j] = hh;
      cs[n*HDIM + j] = cc;
    }
    gridbar(arrive, 2*n + 2);
  }
}

// ---------- generic accumulating GEMM: C[n,h] += sum_k A[rowmap(n),k]*B[h,k] ----------
// rowmap: src = n - shift (wrap mod NROWS, replicating torch negative-index wrap),
// contribution zero when n < minn. A lda = K, B ldb = K, C ldc = HDIM.
__global__ __launch_bounds__(256) void gemm_acc(
    float* __restrict__ C, const float* __restrict__ A, const float* __restrict__ B,
    int K, int shift, int minn)
{
  __shared__ float Asf[16 * 68];   // [k][row], pad 68 -> <=2-way bank alias (free)
  __shared__ float Bsf[16 * 68];
  const int tid = threadIdx.x;
  const int h0  = blockIdx.x * 64;
  const int n0  = blockIdx.y * 64;
  const int r   = tid >> 2;          // 0..63
  const int kq  = (tid & 3) << 2;    // 0,4,8,12
  const int tx  = tid & 15, ty = tid >> 4;

  int arow = n0 + r;
  int src  = arow - shift; if (src < 0) src += NROWS;
  const bool avalid = (arow >= minn);
  const float* Ap = A + (long)src * K + kq;
  const float* Bp = B + (long)(h0 + r) * K + kq;

  vf4 acc0 = {0.f,0.f,0.f,0.f}, acc1 = {0.f,0.f,0.f,0.f};
  vf4 acc2 = {0.f,0.f,0.f,0.f}, acc3 = {0.f,0.f,0.f,0.f};
  const vf4 zero = {0.f,0.f,0.f,0.f};

  for (int k0 = 0; k0 < K; k0 += 16) {
    vf4 av = avalid ? *(const vf4*)(Ap + k0) : zero;
    vf4 bv = *(const vf4*)(Bp + k0);
    __syncthreads();
    Asf[(kq+0)*68 + r] = av.x;  Asf[(kq+1)*68 + r] = av.y;
    Asf[(kq+2)*68 + r] = av.z;  Asf[(kq+3)*68 + r] = av.w;
    Bsf[(kq+0)*68 + r] = bv.x;  Bsf[(kq+1)*68 + r] = bv.y;
    Bsf[(kq+2)*68 + r] = bv.z;  Bsf[(kq+3)*68 + r] = bv.w;
    __syncthreads();
#pragma unroll
    for (int c = 0; c < 16; ++c) {
      vf4 a = *(const vf4*)(Asf + c*68 + (ty << 2));
      vf4 b = *(const vf4*)(Bsf + c*68 + (tx << 2));
      acc0 += a.x * b;
      acc1 += a.y * b;
      acc2 += a.z * b;
      acc3 += a.w * b;
    }
  }
  float* cp = C + (long)(n0 + (ty << 2)) * HDIM + h0 + (tx << 2);
  { vf4 t = *(vf4*)(cp + 0*HDIM); t += acc0; *(vf4*)(cp + 0*HDIM) = t; }
  { vf4 t = *(vf4*)(cp + 1*HDIM); t += acc1; *(vf4*)(cp + 1*HDIM) = t; }
  { vf4 t = *(vf4*)(cp + 2*HDIM); t += acc2; *(vf4*)(cp + 2*HDIM) = t; }
  { vf4 t = *(vf4*)(cp + 3*HDIM); t += acc3; *(vf4*)(cp + 3*HDIM) = t; }
}

__global__ void bias_init(float* __restrict__ out, const float* __restrict__ bias) {
  int i = blockIdx.x * blockDim.x + threadIdx.x;      // vf4 index
  vf4 v = {0.f,0.f,0.f,0.f};
  if (bias) { int h = (i << 2) & (HDIM - 1); v = *(const vf4*)(bias + h); }
  *((vf4*)out + i) = v;
}

__global__ void sigmoid_k(float* __restrict__ e) {
  int i = blockIdx.x * blockDim.x + threadIdx.x;
  vf4 v = *((vf4*)e + i);
  v.x = fsig(v.x); v.y = fsig(v.y); v.z = fsig(v.z); v.w = fsig(v.w);
  *((vf4*)e + i) = v;
}

extern "C" void kernel_launch(void* const* d_in, const int* in_sizes, int n_in,
                              void* d_out, int out_size, void* d_ws, size_t ws_size,
                              hipStream_t stream) {
  const float* x    = (const float*)d_in[0];
  const float* xw   = (const float*)d_in[1];
  const float* w_ix = (const float*)d_in[2];
  const float* w_ih = (const float*)d_in[3];
  const float* w_ie = (const float*)d_in[4];
  const float* b_i  = (const float*)d_in[5];
  const float* w_fx = (const float*)d_in[6];
  const float* w_fo = (const float*)d_in[7];
  const float* w_fe = (const float*)d_in[8];
  const float* b_f  = (const float*)d_in[9];
  const float* w_ox = (const float*)d_in[10];
  const float* w_oh = (const float*)d_in[11];
  const float* w_oe = (const float*)d_in[12];
  const float* b_o  = (const float*)d_in[13];
  const float* w_gx = (const float*)d_in[14];
  const float* w_gh = (const float*)d_in[15];
  const float* b_g  = (const float*)d_in[16];
  const float* w_d  = (const float*)d_in[17];
  const float* w_w  = (const float*)d_in[18];
  const float* w_m  = (const float*)d_in[19];
  const float* w_t  = (const float*)d_in[20];
  const float* w_e  = (const float*)d_in[21];
  const float* b_e  = (const float*)d_in[22];

  const long S = (long)NROWS * HDIM;
  float* ws_f   = (float*)d_ws;
  float* pre_ho = ws_f + 0*S;
  float* pre_i  = ws_f + 1*S;
  float* pre_g  = ws_f + 2*S;
  float* pre_f  = ws_f + 3*S;
  float* pre_o  = ws_f + 4*S;
  float* e_buf  = ws_f + 5*S;
  float* hbuf   = ws_f + 6*S;
  float* hobuf  = hbuf + HDIM;
  int*   arrive = (int*)(hobuf + HDIM);

  size_t need = (size_t)(6*S + 2*HDIM + GWG) * sizeof(float);
  if (ws_size < need) {
    fprintf(stderr, "kernel_launch: ws too small (have %zu, need %zu)\n", ws_size, need);
    return;
  }

  dim3 ggrid(HDIM/64, NROWS/64);

  bias_init<<<NROWS, 256, 0, stream>>>(pre_i, b_i);
  bias_init<<<NROWS, 256, 0, stream>>>(pre_g, b_g);
  bias_init<<<NROWS, 256, 0, stream>>>(pre_f, b_f);
  bias_init<<<NROWS, 256, 0, stream>>>(pre_o, b_o);
  bias_init<<<NROWS, 256, 0, stream>>>(e_buf, b_e);
  bias_init<<<NROWS, 256, 0, stream>>>(pre_ho, nullptr);

  // e = sigmoid(xw @ w_e^T + b_e)
  gemm_acc<<<ggrid, 256, 0, stream>>>(e_buf, xw, w_e, 64, 0, 0);
  sigmoid_k<<<NROWS, 256, 0, stream>>>(e_buf);

  // x contributions (K=512)
  gemm_acc<<<ggrid, 256, 0, stream>>>(pre_i, x, w_ix, 512, 0, 0);
  gemm_acc<<<ggrid, 256, 0, stream>>>(pre_g, x, w_gx, 512, 0, 0);
  gemm_acc<<<ggrid, 256, 0, stream>>>(pre_f, x, w_fx, 512, 0, 0);
  gemm_acc<<<ggrid, 256, 0, stream>>>(pre_o, x, w_ox, 512, 0, 0);
  // e contributions (K=1024)
  gemm_acc<<<ggrid, 256, 0, stream>>>(pre_i, e_buf, w_ie, 1024, 0, 0);
  gemm_acc<<<ggrid, 256, 0, stream>>>(pre_f, e_buf, w_fe, 1024, 0, 0);
  gemm_acc<<<ggrid, 256, 0, stream>>>(pre_o, e_buf, w_oe, 1024, 0, 0);
  // day-shifted contributions: shift rows = 96*days; mask n>=minn; torch wrap via mod
  gemm_acc<<<ggrid, 256, 0, stream>>>(pre_ho, x, w_d, 512,   96,   96);
  gemm_acc<<<ggrid, 256, 0, stream>>>(pre_ho, x, w_w, 512,  576,  672);
  gemm_acc<<<ggrid, 256, 0, stream>>>(pre_ho, x, w_m, 512, 2784, 2688);

  hipMemsetAsync(arrive, 0, GWG * sizeof(int), stream);

  float* hs = (float*)d_out;
  float* cs = hs + S;
  scan_kernel<<<GWG, 256, 0, stream>>>(pre_ho, pre_i, pre_g, pre_f, pre_o,
                                       w_t, w_ih, w_gh, w_fo, w_oh,
                                       hbuf, hobuf, arrive, hs, cs);
}